// Round 9
// baseline (925.455 us; speedup 1.0000x reference)
//
#include <hip/hip_runtime.h>
#include <hip/hip_bf16.h>
#include <stdint.h>

#define B_ 128
#define L_ 512
#define V_ 256
#define E_ 64
#define H_ 256
#define SC 2.885390081777927f   // 2*log2(e): exp2(SC*z) = e^{2z}

typedef __attribute__((ext_vector_type(8))) __bf16 bf16x8;
typedef __attribute__((ext_vector_type(4))) float f32x4;
typedef __attribute__((ext_vector_type(8))) unsigned short ushort8;

__device__ __forceinline__ unsigned short f2bf(float f) {
    unsigned int u = __builtin_bit_cast(unsigned int, f);
    u += 0x7fffu + ((u >> 16) & 1u);           // RNE
    return (unsigned short)(u >> 16);
}

// ---------------- prologue: embW2 = SC*(emb@W_xh + b_h) ; casts; bias -----
__global__ void prologue_kernel(const float* __restrict__ emb,
                                const float* __restrict__ Wxh,
                                const float* __restrict__ bh,
                                const float* __restrict__ Why,
                                const float* __restrict__ Whyb,
                                const float* __restrict__ by,
                                const float* __restrict__ Whh,
                                float* __restrict__ embW2,
                                unsigned short* __restrict__ whyb16,
                                float* __restrict__ bias,
                                unsigned short* __restrict__ whhT16)
{
    int blk = blockIdx.x, tid = threadIdx.x;
    if (blk < V_) {
        float s = bh[tid];
        #pragma unroll 8
        for (int e = 0; e < E_; ++e)
            s = fmaf(emb[blk * E_ + e], Wxh[e * H_ + tid], s);
        embW2[blk * H_ + tid] = s * SC;
    } else if (blk < 2 * V_) {
        int i = (blk - V_) * 256 + tid;
        whyb16[i] = f2bf(Why[i]);
    } else if (blk == 2 * V_) {
        bias[tid] = Whyb[tid] + by[tid];
    } else {
        int c = blk - (2 * V_ + 1);                       // hcol
        whhT16[c * H_ + tid] = f2bf(Whh[tid * H_ + c] * SC);  // SC*W_hh^T
    }
}

// ---------------- recurrence: 4 blocks x 32 batch rows, 512 steps ---------
// Two independent 16-row tiles per block: waves 0-3 -> tile 0, waves 4-7 ->
// tile 1 (2 waves/SIMD working on data-independent tiles = real TLP).
// Each wave: 64 hcols = 4 fragments, 4 independent 8-deep MFMA chains.
// z^T = (SC*W_hh^T) @ h^T ; D: lane(lhi,l15) -> batch=l15, hcol=hb+f*16+lhi*4+r
__global__ __launch_bounds__(512)
__attribute__((amdgpu_waves_per_eu(2, 2)))
void rnn_rec_kernel(
    const int* __restrict__ x, const float* __restrict__ hidden,
    const float* __restrict__ embW2, const unsigned short* __restrict__ whhT16,
    unsigned short* __restrict__ hs, float* __restrict__ hfin)
{
    __shared__ unsigned short h_lds[2][2][16 * 256];   // [tile][buf], 32 KB

    const int tid  = threadIdx.x;
    const int w    = tid >> 6, lane = tid & 63;
    const int l15  = lane & 15, lhi = lane >> 4;
    const int lhi4 = lhi * 4;
    const int tile = w >> 2, wt = w & 3;            // tile id, wave-in-tile
    const int b0   = blockIdx.x * 32;
    const int brow = b0 + tile * 16 + l15;          // this lane's batch row
    const int hb   = wt * 64;                       // wave's hcol base
    char* ldsbase  = (char*)&h_lds[0][0][0];
    const unsigned tbase = (unsigned)(tile << 14);  // tile stride 16 KB

    // swizzle: byte (row,c2) -> row*512 + (c2 ^ ((row&7)<<4))
    const unsigned swzm = (unsigned)((l15 & 7) << 4);
    // read base: addr(kt,cb) = rb2 ^ ((kt<<6) | (cb<<13))
    const unsigned rb2 = (unsigned)(l15 * 512)
                       + ((unsigned)(lhi * 16) ^ (swzm & 0x30u))
                       + (swzm & 0x40u) + tbase;
    // write base for fragment f: (wab0 ^ (f<<5)) + ((CB^1)<<13)
    // c2 = wt*128 + f*32 + lhi*8; bits 5-6 (f) enter purely by XOR
    const unsigned wab0 = (unsigned)(l15 * 512) + tbase
                        + (((unsigned)(wt * 128 + lhi * 8)) ^ swzm);

    // A-fragments (prescaled W_hh^T): f=0..3 -> hcols hb+f*16+l15, k=kt*32+lhi*8
    bf16x8 afrag[4][8];
    #pragma unroll
    for (int f = 0; f < 4; ++f)
        #pragma unroll
        for (int kt = 0; kt < 8; ++kt)
            afrag[f][kt] = *(const bf16x8*)(whhT16 +
                (hb + f * 16 + l15) * H_ + kt * 32 + lhi * 8);

    // init both h tiles (buf 0) from `hidden` (same swizzle)
    for (int i = tid; i < 32 * 256; i += 512) {
        int row32 = i >> 8, c = i & 255;
        int trow = row32 & 15;
        *(unsigned short*)(ldsbase + ((row32 >> 4) * 16384 + trow * 512 +
            ((c * 2) ^ ((trow & 7) << 4)))) =
            f2bf(hidden[(b0 + row32) * H_ + c]);
    }

    // pipelined gather state
    const char* e8 = (const char*)embW2;
    const unsigned go = (unsigned)((hb + lhi4) * 4);   // + f*64 bytes
    const int* xp = x + brow * L_ + 2;
    char* hsp = (char*)hs + (size_t)brow * L_ * (H_ * 2) + (hb + lhi4) * 2;

    int xvA = x[brow * L_ + 0];
    f32x4 eA[4], eB[4];
    {
        unsigned v0 = ((unsigned)xvA << 10) + go;
        #pragma unroll
        for (int f = 0; f < 4; ++f)
            eA[f] = *(const f32x4*)(e8 + v0 + f * 64);
    }
    int xvB = x[brow * L_ + 1];

    __syncthreads();

    auto phase = [&](f32x4 (&ec)[4], f32x4 (&en)[4],
                     int xg, int& xf, int CB, bool PG, bool PX, bool FIN)
                     __attribute__((always_inline)) {
        // 1. LDS reads first (feed MFMAs ASAP); wave reads ONLY its tile
        bf16x8 hv[8];
        #pragma unroll
        for (int kt = 0; kt < 8; ++kt)
            hv[kt] = *(const bf16x8*)(ldsbase +
                       (rb2 ^ (unsigned)((kt << 6) | (CB << 13))));

        // 2. next-step gathers (consumed next step; full step of slack)
        if (PG) {
            unsigned vo = ((unsigned)xg << 10) + go;
            #pragma unroll
            for (int f = 0; f < 4; ++f)
                en[f] = *(const f32x4*)(e8 + vo + f * 64);
        }
        if (PX) { xf = *xp; ++xp; }

        // 3. four independent 8-deep chains, round-robin issue
        f32x4 z0 = ec[0], z1 = ec[1], z2 = ec[2], z3 = ec[3];
        #pragma unroll
        for (int kt = 0; kt < 8; ++kt) {
            z0 = __builtin_amdgcn_mfma_f32_16x16x32_bf16(afrag[0][kt], hv[kt], z0, 0, 0, 0);
            z1 = __builtin_amdgcn_mfma_f32_16x16x32_bf16(afrag[1][kt], hv[kt], z1, 0, 0, 0);
            z2 = __builtin_amdgcn_mfma_f32_16x16x32_bf16(afrag[2][kt], hv[kt], z2, 0, 0, 0);
            z3 = __builtin_amdgcn_mfma_f32_16x16x32_bf16(afrag[3][kt], hv[kt], z3, 0, 0, 0);
        }

        // 4. tanh + writes (partner wave on this SIMD overlaps its MFMAs)
        f32x4 zz[4] = {z0, z1, z2, z3};
        f32x4 th[4];
        uint2 p[4];
        #pragma unroll
        for (int f = 0; f < 4; ++f) {
            #pragma unroll
            for (int r = 0; r < 4; ++r) {
                float e = __builtin_exp2f(zz[f][r]);
                th[f][r] = fmaf(-2.0f, __builtin_amdgcn_rcpf(e + 1.0f), 1.0f);
            }
            asm("v_cvt_pk_bf16_f32 %0, %1, %2" : "=v"(p[f].x) : "v"(th[f][0]), "v"(th[f][1]));
            asm("v_cvt_pk_bf16_f32 %0, %1, %2" : "=v"(p[f].y) : "v"(th[f][2]), "v"(th[f][3]));
            *(uint2*)(ldsbase + ((wab0 ^ (unsigned)(f << 5)) + ((CB ^ 1) << 13))) = p[f];
            *(uint2*)(hsp + f * 32) = p[f];     // fire-and-forget
        }
        hsp += 512;

        if (FIN) {
            #pragma unroll
            for (int f = 0; f < 4; ++f)
                *(f32x4*)(hfin + brow * H_ + hb + f * 16 + lhi4) = th[f];
        }

        // 5. LDS-only barrier (global stores stay in flight)
        __builtin_amdgcn_sched_barrier(0);
        asm volatile("s_waitcnt lgkmcnt(0)" ::: "memory");
        __builtin_amdgcn_s_barrier();
        __builtin_amdgcn_sched_barrier(0);
    };

    // t = 0..509 (both phases prefetch gather + x)
    for (int i = 0; i < 255; ++i) {
        phase(eA, eB, xvB, xvA, 0, true, true, false);
        phase(eB, eA, xvA, xvB, 1, true, true, false);
    }
    // t = 510: gather for 511 (xg = x[511]), no x-load
    phase(eA, eB, xvB, xvA, 0, true, false, false);
    // t = 511: no prefetch, write final hidden
    phase(eB, eA, 0, xvB, 1, false, false, true);
}

// ---------------- logits: hs[65536,256] @ W_hy^T + bias -------------------
__global__ __launch_bounds__(256, 1) void logits_kernel(
    const unsigned short* __restrict__ hs,
    const unsigned short* __restrict__ whyb16,
    const float* __restrict__ bias,
    float* __restrict__ logits)
{
    __shared__ unsigned short a_lds[2][32 * 256];   // 2 x 16KB, swizzled

    const int tid = threadIdx.x;
    const int w = tid >> 6, lane = tid & 63;
    const int l15 = lane & 15, lhi = lane >> 4;
    const size_t rowblk = (size_t)blockIdx.x * 256;

    int col[4];
    #pragma unroll
    for (int n = 0; n < 4; ++n) col[n] = w * 64 + n * 16 + l15;

    bf16x8 bfrag[4][8];
    #pragma unroll
    for (int n = 0; n < 4; ++n)
        #pragma unroll
        for (int kt = 0; kt < 8; ++kt)
            bfrag[n][kt] = *(const bf16x8*)(whyb16 + col[n] * H_ + kt * 32 + lhi * 8);

    float bv[4];
    #pragma unroll
    for (int n = 0; n < 4; ++n) bv[n] = bias[col[n]];

    auto swz = [](unsigned row, unsigned inrow) -> unsigned {
        return row * 512u + (inrow ^ ((row & 7u) << 4));
    };

    #pragma unroll
    for (int ii = 0; ii < 4; ++ii) {
        unsigned Lg = (unsigned)(ii * 256 + tid) * 16u;
        unsigned row = Lg >> 9, inrow = Lg & 511u;
        ushort8 v = *(const ushort8*)((const char*)hs +
                     ((rowblk + row) * 512u + inrow));
        *(ushort8*)((char*)a_lds[0] + swz(row, inrow)) = v;
    }
    __syncthreads();

    for (int c = 0; c < 8; ++c) {
        const int cb = c & 1;
        ushort8 vs[4];
        unsigned srow[4], sinrow[4];
        if (c < 7) {
            #pragma unroll
            for (int ii = 0; ii < 4; ++ii) {
                unsigned Lg = (unsigned)(ii * 256 + tid) * 16u;
                srow[ii] = Lg >> 9; sinrow[ii] = Lg & 511u;
                vs[ii] = *(const ushort8*)((const char*)hs +
                          ((rowblk + (size_t)(c + 1) * 32 + srow[ii]) * 512u + sinrow[ii]));
            }
        }

        #pragma unroll
        for (int m = 0; m < 2; ++m) {
            f32x4 acc[4];
            #pragma unroll
            for (int n = 0; n < 4; ++n) acc[n] = f32x4{0.f, 0.f, 0.f, 0.f};
            #pragma unroll
            for (int kt = 0; kt < 8; ++kt) {
                unsigned rl = (unsigned)(m * 16 + l15);
                bf16x8 a = *(const bf16x8*)((const char*)a_lds[cb] +
                            swz(rl, (unsigned)(kt * 64 + lhi * 16)));
                #pragma unroll
                for (int n = 0; n < 4; ++n)
                    acc[n] = __builtin_amdgcn_mfma_f32_16x16x32_bf16(
                                 a, bfrag[n][kt], acc[n], 0, 0, 0);
            }
            size_t grow = rowblk + (size_t)c * 32 + m * 16 + lhi * 4;
            #pragma unroll
            for (int n = 0; n < 4; ++n)
                #pragma unroll
                for (int r = 0; r < 4; ++r)
                    logits[(grow + r) * V_ + col[n]] = acc[n][r] + bv[n];
        }
        if (c < 7) {
            #pragma unroll
            for (int ii = 0; ii < 4; ++ii)
                *(ushort8*)((char*)a_lds[cb ^ 1] + swz(srow[ii], sinrow[ii])) = vs[ii];
        }
        __syncthreads();
    }
}

extern "C" void kernel_launch(void* const* d_in, const int* in_sizes, int n_in,
                              void* d_out, int out_size, void* d_ws, size_t ws_size,
                              hipStream_t stream) {
    const int*   x      = (const int*)d_in[0];
    const float* hidden = (const float*)d_in[1];
    const float* emb    = (const float*)d_in[2];
    const float* Wxh    = (const float*)d_in[3];
    const float* Whh    = (const float*)d_in[4];
    const float* bh     = (const float*)d_in[5];
    const float* Why    = (const float*)d_in[6];
    const float* Whyb   = (const float*)d_in[7];
    const float* by     = (const float*)d_in[8];

    float* out = (float*)d_out;
    char*  ws  = (char*)d_ws;

    unsigned short* hs     = (unsigned short*)ws;                  // 33,554,432 B
    float*          embW2  = (float*)(ws + 33554432);              //    262,144 B
    unsigned short* whyb16 = (unsigned short*)(ws + 33816576);     //    131,072 B
    float*          bias   = (float*)(ws + 33947648);              //      1,024 B
    unsigned short* whhT16 = (unsigned short*)(ws + 33948672);     //    131,072 B

    prologue_kernel<<<2 * V_ + 1 + V_, 256, 0, stream>>>(emb, Wxh, bh, Why, Whyb, by, Whh,
                                                         embW2, whyb16, bias, whhT16);
    rnn_rec_kernel<<<B_ / 32, 512, 0, stream>>>(x, hidden, embW2, whhT16,
                                                hs, out + (size_t)B_ * L_ * V_);
    logits_kernel<<<(B_ * L_) / 256, 256, 0, stream>>>(hs, whyb16, bias, out);
}

// Round 10
// 454.171 us; speedup vs baseline: 2.0377x; 2.0377x over previous
//
#include <hip/hip_runtime.h>
#include <hip/hip_bf16.h>
#include <stdint.h>

#define B_ 128
#define L_ 512
#define V_ 256
#define E_ 64
#define H_ 256
#define SC 2.885390081777927f   // 2*log2(e): exp2(SC*z) = e^{2z}

typedef __attribute__((ext_vector_type(8))) __bf16 bf16x8;
typedef __attribute__((ext_vector_type(4))) float f32x4;
typedef __attribute__((ext_vector_type(8))) unsigned short ushort8;

__device__ __forceinline__ unsigned short f2bf(float f) {
    unsigned int u = __builtin_bit_cast(unsigned int, f);
    u += 0x7fffu + ((u >> 16) & 1u);           // RNE
    return (unsigned short)(u >> 16);
}

// ---------------- prologue: embW2 = SC*(emb@W_xh + b_h) ; casts; bias -----
__global__ void prologue_kernel(const float* __restrict__ emb,
                                const float* __restrict__ Wxh,
                                const float* __restrict__ bh,
                                const float* __restrict__ Why,
                                const float* __restrict__ Whyb,
                                const float* __restrict__ by,
                                const float* __restrict__ Whh,
                                float* __restrict__ embW2,
                                unsigned short* __restrict__ whyb16,
                                float* __restrict__ bias,
                                unsigned short* __restrict__ whhT16)
{
    int blk = blockIdx.x, tid = threadIdx.x;
    if (blk < V_) {
        float s = bh[tid];
        #pragma unroll 8
        for (int e = 0; e < E_; ++e)
            s = fmaf(emb[blk * E_ + e], Wxh[e * H_ + tid], s);
        embW2[blk * H_ + tid] = s * SC;
    } else if (blk < 2 * V_) {
        int i = (blk - V_) * 256 + tid;
        whyb16[i] = f2bf(Why[i]);
    } else if (blk == 2 * V_) {
        bias[tid] = Whyb[tid] + by[tid];
    } else {
        int c = blk - (2 * V_ + 1);                       // hcol
        whhT16[c * H_ + tid] = f2bf(Whh[tid * H_ + c] * SC);  // SC*W_hh^T
    }
}

// ---------------- recurrence: 8 blocks x 16 batch rows, 512 steps ---------
// 4 waves x 64 hcols each (4 fragments). z^T = (SC*W_hh^T) @ h^T.
// D layout (m89): lane(lhi,l15) -> batch=l15, hcol = hb_f + lhi*4 + r.
// R4-measured best config (427 us). waves_per_eu(1,1): 1 block/CU anyway ->
// give the allocator the full 512-VGPR budget for load pipelining.
__global__ __launch_bounds__(256)
__attribute__((amdgpu_waves_per_eu(1, 1)))
void rnn_rec_kernel(
    const int* __restrict__ x, const float* __restrict__ hidden,
    const float* __restrict__ embW2, const unsigned short* __restrict__ whhT16,
    unsigned short* __restrict__ hs, float* __restrict__ hfin)
{
    __shared__ unsigned short h_lds[2][16 * 256];   // swizzled bf16, dbuf

    const int tid  = threadIdx.x;
    const int w    = tid >> 6, lane = tid & 63;
    const int l15  = lane & 15, lhi = lane >> 4;
    const int lhi4 = lhi * 4;
    const int b0   = blockIdx.x * 16;
    char* ldsbase  = (char*)&h_lds[0][0];

    // swizzle: byte (row,c2) -> row*512 + (c2 ^ ((row&7)<<4))
    const unsigned swzm = (unsigned)((l15 & 7) << 4);
    const unsigned rb2 = (unsigned)(l15 * 512)
                       + ((unsigned)(lhi * 16) ^ (swzm & 0x30u))
                       + (swzm & 0x40u);
    const unsigned wab0 = (unsigned)(l15 * 512)
                        + (unsigned)(w * 128)
                        + (((unsigned)(lhi * 8)) ^ (swzm & 0x10u))
                        + (swzm & 0x60u);

    // persistent A-fragments (prescaled W_hh^T): f=0..3 -> hcols w*64+f*16+..
    bf16x8 afrag[4][8];
    #pragma unroll
    for (int f = 0; f < 4; ++f)
        #pragma unroll
        for (int kt = 0; kt < 8; ++kt)
            afrag[f][kt] = *(const bf16x8*)(whhT16 +
                (w * 64 + f * 16 + l15) * H_ + kt * 32 + lhi * 8);

    // init h buffer 0 from `hidden` (same swizzle)
    for (int i = tid; i < 16 * 256; i += 256) {
        int row = i >> 8, c = i & 255;
        *(unsigned short*)(ldsbase + (row * 512 + ((c * 2) ^ ((row & 7) << 4)))) =
            f2bf(hidden[(b0 + row) * H_ + c]);
    }

    // pipelined gather state
    const char* e8 = (const char*)embW2;
    const unsigned go = (unsigned)((w * 64 + lhi4) * 4);   // + f*64 bytes
    const int* xp = x + (b0 + l15) * L_ + 2;
    char* hsp = (char*)hs + (size_t)(b0 + l15) * L_ * (H_ * 2) + (w * 64 + lhi4) * 2;

    int xvA = x[(b0 + l15) * L_ + 0];
    f32x4 eA[4], eB[4];
    {
        unsigned v0 = ((unsigned)xvA << 10) + go;
        #pragma unroll
        for (int f = 0; f < 4; ++f)
            eA[f] = *(const f32x4*)(e8 + v0 + f * 64);
    }
    int xvB = x[(b0 + l15) * L_ + 1];

    __syncthreads();

    auto phase = [&](f32x4 (&ec)[4], f32x4 (&en)[4],
                     int xg, int& xf, int CB, bool PG, bool PX, bool FIN)
                     __attribute__((always_inline)) {
        // 1. issue next-step gathers FIRST (before stores: in-order vmcnt)
        if (PG) {
            unsigned vo = ((unsigned)xg << 10) + go;
            #pragma unroll
            for (int f = 0; f < 4; ++f)
                en[f] = *(const f32x4*)(e8 + vo + f * 64);
        }
        if (PX) { xf = *xp; ++xp; }

        // 2. LDS reads: full h tile as B-operand (shared by all 4 chains)
        bf16x8 hv[8];
        #pragma unroll
        for (int kt = 0; kt < 8; ++kt)
            hv[kt] = *(const bf16x8*)(ldsbase +
                       (rb2 ^ (unsigned)((kt << 6) | (CB << 13))));

        f32x4 acc[4];
        #pragma unroll
        for (int f = 0; f < 4; ++f) acc[f] = ec[f];

        f32x4 th[4];
        uint2 p[4];

        // 3. chain f0 first; then chain f+1 emitted alongside tanh(f):
        //    the MFMA pipe and VALU/trans pipe overlap within the wave.
        #pragma unroll
        for (int kt = 0; kt < 8; ++kt)
            acc[0] = __builtin_amdgcn_mfma_f32_16x16x32_bf16(afrag[0][kt], hv[kt], acc[0], 0, 0, 0);

        #pragma unroll
        for (int f = 0; f < 4; ++f) {
            if (f < 3) {
                #pragma unroll
                for (int kt = 0; kt < 8; ++kt)
                    acc[f + 1] = __builtin_amdgcn_mfma_f32_16x16x32_bf16(
                                     afrag[f + 1][kt], hv[kt], acc[f + 1], 0, 0, 0);
            }
            // tanh(acc[f]) (input pre-scaled): th = 1 - 2/(exp2(acc)+1)
            #pragma unroll
            for (int r = 0; r < 4; ++r) {
                float e = __builtin_exp2f(acc[f][r]);
                th[f][r] = fmaf(-2.0f, __builtin_amdgcn_rcpf(e + 1.0f), 1.0f);
            }
            asm("v_cvt_pk_bf16_f32 %0, %1, %2" : "=v"(p[f].x) : "v"(th[f][0]), "v"(th[f][1]));
            asm("v_cvt_pk_bf16_f32 %0, %1, %2" : "=v"(p[f].y) : "v"(th[f][2]), "v"(th[f][3]));
            // h chunk f -> other LDS buffer
            *(uint2*)(ldsbase + ((wab0 ^ (unsigned)(f << 5)) + ((CB ^ 1) << 13))) = p[f];
            // hs chunk f (fire-and-forget)
            *(uint2*)(hsp + f * 32) = p[f];
        }
        hsp += 512;

        if (FIN) {
            #pragma unroll
            for (int f = 0; f < 4; ++f)
                *(f32x4*)(hfin + (b0 + l15) * H_ + w * 64 + f * 16 + lhi4) = th[f];
        }

        // 4. LDS-only barrier (global stores stay in flight)
        __builtin_amdgcn_sched_barrier(0);
        asm volatile("s_waitcnt lgkmcnt(0)" ::: "memory");
        __builtin_amdgcn_s_barrier();
        __builtin_amdgcn_sched_barrier(0);
    };

    // t = 0..509 (both phases prefetch gather + x)
    for (int i = 0; i < 255; ++i) {
        phase(eA, eB, xvB, xvA, 0, true, true, false);
        phase(eB, eA, xvA, xvB, 1, true, true, false);
    }
    // t = 510: gather for 511 (xg = x[511]), no x-load
    phase(eA, eB, xvB, xvA, 0, true, false, false);
    // t = 511: no prefetch, write final hidden
    phase(eB, eA, 0, xvB, 1, false, false, true);
}

// ---------------- logits: hs[65536,256] @ W_hy^T + bias -------------------
__global__ __launch_bounds__(256, 1) void logits_kernel(
    const unsigned short* __restrict__ hs,
    const unsigned short* __restrict__ whyb16,
    const float* __restrict__ bias,
    float* __restrict__ logits)
{
    __shared__ unsigned short a_lds[2][32 * 256];   // 2 x 16KB, swizzled

    const int tid = threadIdx.x;
    const int w = tid >> 6, lane = tid & 63;
    const int l15 = lane & 15, lhi = lane >> 4;
    const size_t rowblk = (size_t)blockIdx.x * 256;

    int col[4];
    #pragma unroll
    for (int n = 0; n < 4; ++n) col[n] = w * 64 + n * 16 + l15;

    bf16x8 bfrag[4][8];
    #pragma unroll
    for (int n = 0; n < 4; ++n)
        #pragma unroll
        for (int kt = 0; kt < 8; ++kt)
            bfrag[n][kt] = *(const bf16x8*)(whyb16 + col[n] * H_ + kt * 32 + lhi * 8);

    float bv[4];
    #pragma unroll
    for (int n = 0; n < 4; ++n) bv[n] = bias[col[n]];

    auto swz = [](unsigned row, unsigned inrow) -> unsigned {
        return row * 512u + (inrow ^ ((row & 7u) << 4));
    };

    #pragma unroll
    for (int ii = 0; ii < 4; ++ii) {
        unsigned Lg = (unsigned)(ii * 256 + tid) * 16u;
        unsigned row = Lg >> 9, inrow = Lg & 511u;
        ushort8 v = *(const ushort8*)((const char*)hs +
                     ((rowblk + row) * 512u + inrow));
        *(ushort8*)((char*)a_lds[0] + swz(row, inrow)) = v;
    }
    __syncthreads();

    for (int c = 0; c < 8; ++c) {
        const int cb = c & 1;
        ushort8 vs[4];
        unsigned srow[4], sinrow[4];
        if (c < 7) {
            #pragma unroll
            for (int ii = 0; ii < 4; ++ii) {
                unsigned Lg = (unsigned)(ii * 256 + tid) * 16u;
                srow[ii] = Lg >> 9; sinrow[ii] = Lg & 511u;
                vs[ii] = *(const ushort8*)((const char*)hs +
                          ((rowblk + (size_t)(c + 1) * 32 + srow[ii]) * 512u + sinrow[ii]));
            }
        }

        #pragma unroll
        for (int m = 0; m < 2; ++m) {
            f32x4 acc[4];
            #pragma unroll
            for (int n = 0; n < 4; ++n) acc[n] = f32x4{0.f, 0.f, 0.f, 0.f};
            #pragma unroll
            for (int kt = 0; kt < 8; ++kt) {
                unsigned rl = (unsigned)(m * 16 + l15);
                bf16x8 a = *(const bf16x8*)((const char*)a_lds[cb] +
                            swz(rl, (unsigned)(kt * 64 + lhi * 16)));
                #pragma unroll
                for (int n = 0; n < 4; ++n)
                    acc[n] = __builtin_amdgcn_mfma_f32_16x16x32_bf16(
                                 a, bfrag[n][kt], acc[n], 0, 0, 0);
            }
            size_t grow = rowblk + (size_t)c * 32 + m * 16 + lhi * 4;
            #pragma unroll
            for (int n = 0; n < 4; ++n)
                #pragma unroll
                for (int r = 0; r < 4; ++r)
                    logits[(grow + r) * V_ + col[n]] = acc[n][r] + bv[n];
        }
        if (c < 7) {
            #pragma unroll
            for (int ii = 0; ii < 4; ++ii)
                *(ushort8*)((char*)a_lds[cb ^ 1] + swz(srow[ii], sinrow[ii])) = vs[ii];
        }
        __syncthreads();
    }
}

extern "C" void kernel_launch(void* const* d_in, const int* in_sizes, int n_in,
                              void* d_out, int out_size, void* d_ws, size_t ws_size,
                              hipStream_t stream) {
    const int*   x      = (const int*)d_in[0];
    const float* hidden = (const float*)d_in[1];
    const float* emb    = (const float*)d_in[2];
    const float* Wxh    = (const float*)d_in[3];
    const float* Whh    = (const float*)d_in[4];
    const float* bh     = (const float*)d_in[5];
    const float* Why    = (const float*)d_in[6];
    const float* Whyb   = (const float*)d_in[7];
    const float* by     = (const float*)d_in[8];

    float* out = (float*)d_out;
    char*  ws  = (char*)d_ws;

    unsigned short* hs     = (unsigned short*)ws;                  // 33,554,432 B
    float*          embW2  = (float*)(ws + 33554432);              //    262,144 B
    unsigned short* whyb16 = (unsigned short*)(ws + 33816576);     //    131,072 B
    float*          bias   = (float*)(ws + 33947648);              //      1,024 B
    unsigned short* whhT16 = (unsigned short*)(ws + 33948672);     //    131,072 B

    prologue_kernel<<<2 * V_ + 1 + V_, 256, 0, stream>>>(emb, Wxh, bh, Why, Whyb, by, Whh,
                                                         embW2, whyb16, bias, whhT16);
    rnn_rec_kernel<<<B_ / 16, 256, 0, stream>>>(x, hidden, embW2, whhT16,
                                                hs, out + (size_t)B_ * L_ * V_);
    logits_kernel<<<(B_ * L_) / 256, 256, 0, stream>>>(hs, whyb16, bias, out);
}